// Round 1
// baseline (76.828 us; speedup 1.0000x reference)
//
#include <hip/hip_runtime.h>

// Trilinear x2 upsample, fused all 3 spatial axes.
// in:  [2,128,128,128,2] f32  (read as float2 over the C=2 channel pair)
// out: [2,256,256,256,2] f32  (written as float4 = {even_w c0,c1, odd_w c0,c1})

__device__ __forceinline__ float2 lerp2(float2 a, float2 b, float w) {
    return make_float2(a.x + w * (b.x - a.x), a.y + w * (b.y - a.y));
}

__global__ __launch_bounds__(256) void resize_trilinear_x2(
    const float2* __restrict__ in, float4* __restrict__ out)
{
    // total threads = 2 * 256 * 256 * 128 = 16,777,216 (exact launch)
    unsigned t = blockIdx.x * blockDim.x + threadIdx.x;
    int ow2 = t & 127;          // W/2 index (innermost -> coalesced)
    int oh  = (t >> 7) & 255;   // wave-uniform
    int od  = (t >> 15) & 255;  // wave-uniform
    int b   = (int)(t >> 23);

    int id0 = od >> 1, id1 = min(id0 + 1, 127);
    int ih0 = oh >> 1, ih1 = min(ih0 + 1, 127);
    int iw0 = ow2,     iw1 = min(iw0 + 1, 127);
    // voxelmorph clip semantics at zoom=2: even coord -> w=0; odd -> w=0.5;
    // last output (o=255) clips to x=127 -> w=0.
    float wd = ((od & 1) && od != 255) ? 0.5f : 0.0f;   // wave-uniform
    float wh = ((oh & 1) && oh != 255) ? 0.5f : 0.0f;   // wave-uniform
    float ww = (iw0 != 127) ? 0.5f : 0.0f;              // per-lane (only lane 127 differs)

    const size_t bb = (size_t)b * 128;

    // Interp one D-plane: returns (even-w value, odd-w value) after H,W lerp.
    auto plane = [&](int d, float2& ve, float2& vo) {
        size_t row0 = ((bb + d) * 128 + ih0) * 128;
        float2 a0 = in[row0 + iw0];
        float2 a1 = in[row0 + iw1];
        ve = a0;
        vo = lerp2(a0, a1, ww);
        if (wh != 0.0f) {   // wave-uniform branch: skip second H row when w=0
            size_t row1 = ((bb + d) * 128 + ih1) * 128;
            float2 b0 = in[row1 + iw0];
            float2 b1 = in[row1 + iw1];
            ve = lerp2(ve, b0, wh);
            vo = lerp2(vo, lerp2(b0, b1, ww), wh);
        }
    };

    float2 ve, vo;
    plane(id0, ve, vo);
    if (wd != 0.0f) {       // wave-uniform branch: skip second D plane when w=0
        float2 ve1, vo1;
        plane(id1, ve1, vo1);
        ve = lerp2(ve, ve1, wd);
        vo = lerp2(vo, vo1, wd);
    }

    // out float4 index: (((b*256+od)*256+oh)*256 + 2*ow2)*2 floats / 4
    size_t oidx = ((size_t)((b * 256 + od) * 256 + oh) * 128) + (size_t)ow2;
    out[oidx] = make_float4(ve.x, ve.y, vo.x, vo.y);
}

extern "C" void kernel_launch(void* const* d_in, const int* in_sizes, int n_in,
                              void* d_out, int out_size, void* d_ws, size_t ws_size,
                              hipStream_t stream) {
    const float2* in = (const float2*)d_in[0];
    float4* out = (float4*)d_out;
    const unsigned total = 2u * 256u * 256u * 128u;  // 16,777,216 threads
    resize_trilinear_x2<<<total / 256u, 256, 0, stream>>>(in, out);
}

// Round 3
// 49.343 us; speedup vs baseline: 1.5570x; 1.5570x over previous
//
#include <hip/hip_runtime.h>

// Trilinear x2 upsample, zoom=2, voxelmorph clip semantics.
// in:  [2,128,128,128,2] f32  (read as float2 over C=2)
// out: [2,256,256,256,2] f32  (written as native float4 = {w-even c0,c1, w-odd c0,c1})
//
// Each thread owns one input voxel position (b,d,h,w2) and produces the full
// 2x2x2 output cube. With clamped corner indices, the boundary "w=0" cases of
// the reference (o=255 -> copy of plane 127) reduce to 0.5*(x+x)=x, so all
// weights are uniformly 0.5 -- no branches.

typedef float f4 __attribute__((ext_vector_type(4)));   // native vector: OK for nontemporal builtin
typedef float f2 __attribute__((ext_vector_type(2)));

__device__ __forceinline__ f2 avg2(f2 a, f2 b) { return 0.5f * (a + b); }

__global__ __launch_bounds__(256) void resize_trilinear_x2(
    const f2* __restrict__ in, f4* __restrict__ out)
{
    // total threads = 2 * 128^3 = 4,194,304
    unsigned t = blockIdx.x * blockDim.x + threadIdx.x;
    int w2 = t & 127;            // input W index (innermost -> coalesced)
    int h  = (t >> 7) & 127;
    int d  = (t >> 14) & 127;
    int b  = (int)(t >> 21);

    int w1 = min(w2 + 1, 127);
    int h1 = min(h + 1, 127);
    int d1 = min(d + 1, 127);

    const size_t base = (size_t)b * (128 * 128 * 128);
    auto idx = [&](int dd, int hh, int ww) -> size_t {
        return base + ((size_t)dd * 128 + (size_t)hh) * 128 + (size_t)ww;
    };

    // 8 corners (each f2 over channels)
    f2 p000 = in[idx(d,  h,  w2)], p001 = in[idx(d,  h,  w1)];
    f2 p010 = in[idx(d,  h1, w2)], p011 = in[idx(d,  h1, w1)];
    f2 p100 = in[idx(d1, h,  w2)], p101 = in[idx(d1, h,  w1)];
    f2 p110 = in[idx(d1, h1, w2)], p111 = in[idx(d1, h1, w1)];

    // d-averaged plane (odd output d)
    f2 q00 = avg2(p000, p100), q01 = avg2(p001, p101);
    f2 q10 = avg2(p010, p110), q11 = avg2(p011, p111);

    const int od = 2 * d, oh = 2 * h;
    // out f4 index: ((b*256 + od)*256 + oh)*128 + w2
    size_t o = ((size_t)((b * 256 + od) * 256 + oh) * 128) + (size_t)w2;
    const size_t OH = 128;            // one output row of f4
    const size_t OD = 256 * 128;      // one output plane of f4

    auto st = [&](size_t at, f2 e, f2 odd) {
        f4 v; v.x = e.x; v.y = e.y; v.z = odd.x; v.w = odd.y;
        __builtin_nontemporal_store(v, &out[at]);
    };

    // plane A = even od (pure p0**), plane B = odd od (q**)
    st(o,      p000, avg2(p000, p001));
    {
        f2 r0 = avg2(p000, p010), r1 = avg2(p001, p011);
        st(o + OH, r0, avg2(r0, r1));
    }
    st(o + OD, q00, avg2(q00, q01));
    {
        f2 r0 = avg2(q00, q10), r1 = avg2(q01, q11);
        st(o + OD + OH, r0, avg2(r0, r1));
    }
}

extern "C" void kernel_launch(void* const* d_in, const int* in_sizes, int n_in,
                              void* d_out, int out_size, void* d_ws, size_t ws_size,
                              hipStream_t stream) {
    const f2* in = (const f2*)d_in[0];
    f4* out = (f4*)d_out;
    const unsigned total = 2u * 128u * 128u * 128u;  // 4,194,304 threads
    resize_trilinear_x2<<<total / 256u, 256, 0, stream>>>(in, out);
}

// Round 4
// 48.315 us; speedup vs baseline: 1.5901x; 1.0213x over previous
//
#include <hip/hip_runtime.h>

// Trilinear x2 upsample, zoom=2, voxelmorph clip semantics.
// in:  [2,128,128,128,2] f32  (read as f2 over C=2)
// out: [2,256,256,256,2] f32  (written as native f4 = {w-even c0,c1, w-odd c0,c1})
//
// One thread = one input voxel -> full 2x2x2 output cube (4x f4 nt stores).
// Clamped corner indices make all boundary cases collapse to 0.5*(x+x)=x.
// Round 4: XCD-contiguous blockIdx swizzle (T1) so each XCD's 4MB L2 holds its
// contiguous 1/8 input slab -> h+2-row and d+1-plane re-reads become L2 hits.

typedef float f4 __attribute__((ext_vector_type(4)));
typedef float f2 __attribute__((ext_vector_type(2)));

__device__ __forceinline__ f2 avg2(f2 a, f2 b) { return 0.5f * (a + b); }

__global__ __launch_bounds__(256) void resize_trilinear_x2(
    const f2* __restrict__ in, f4* __restrict__ out)
{
    // grid = 16384 blocks (divisible by 8 -> simple bijective XCD swizzle)
    unsigned bid = blockIdx.x;
    unsigned swz = (bid & 7u) * 2048u + (bid >> 3);   // XCD-contiguous chunks
    unsigned t = swz * 256u + threadIdx.x;

    int w2 = t & 127;            // input W index (innermost -> coalesced)
    int h  = (t >> 7) & 127;
    int d  = (t >> 14) & 127;
    int b  = (int)(t >> 21);

    int w1 = min(w2 + 1, 127);
    int h1 = min(h + 1, 127);
    int d1 = min(d + 1, 127);

    const size_t base = (size_t)b * (128 * 128 * 128);
    auto idx = [&](int dd, int hh, int ww) -> size_t {
        return base + ((size_t)dd * 128 + (size_t)hh) * 128 + (size_t)ww;
    };

    // 8 corners (each f2 over channels)
    f2 p000 = in[idx(d,  h,  w2)], p001 = in[idx(d,  h,  w1)];
    f2 p010 = in[idx(d,  h1, w2)], p011 = in[idx(d,  h1, w1)];
    f2 p100 = in[idx(d1, h,  w2)], p101 = in[idx(d1, h,  w1)];
    f2 p110 = in[idx(d1, h1, w2)], p111 = in[idx(d1, h1, w1)];

    // d-averaged plane (odd output d)
    f2 q00 = avg2(p000, p100), q01 = avg2(p001, p101);
    f2 q10 = avg2(p010, p110), q11 = avg2(p011, p111);

    const int od = 2 * d, oh = 2 * h;
    // out f4 index: ((b*256 + od)*256 + oh)*128 + w2
    size_t o = ((size_t)((b * 256 + od) * 256 + oh) * 128) + (size_t)w2;
    const size_t OH = 128;            // one output row of f4
    const size_t OD = 256 * 128;      // one output plane of f4

    auto st = [&](size_t at, f2 e, f2 odd) {
        f4 v; v.x = e.x; v.y = e.y; v.z = odd.x; v.w = odd.y;
        __builtin_nontemporal_store(v, &out[at]);
    };

    // plane A = even od (pure p0**), plane B = odd od (q**)
    st(o,      p000, avg2(p000, p001));
    {
        f2 r0 = avg2(p000, p010), r1 = avg2(p001, p011);
        st(o + OH, r0, avg2(r0, r1));
    }
    st(o + OD, q00, avg2(q00, q01));
    {
        f2 r0 = avg2(q00, q10), r1 = avg2(q01, q11);
        st(o + OD + OH, r0, avg2(r0, r1));
    }
}

extern "C" void kernel_launch(void* const* d_in, const int* in_sizes, int n_in,
                              void* d_out, int out_size, void* d_ws, size_t ws_size,
                              hipStream_t stream) {
    const f2* in = (const f2*)d_in[0];
    f4* out = (f4*)d_out;
    const unsigned total = 2u * 128u * 128u * 128u;  // 4,194,304 threads
    resize_trilinear_x2<<<total / 256u, 256, 0, stream>>>(in, out);
}